// Round 5
// baseline (739.121 us; speedup 1.0000x reference)
//
#include <hip/hip_runtime.h>
#include <math.h>

#define Nn 2048
#define Dd 128
#define Ee 8
#define NIT 8
#define KT (Nn*Ee)   // 16384
#define KSPLIT 16

typedef __bf16 bf16;
typedef __attribute__((ext_vector_type(8))) __bf16 bf16x8;
typedef __attribute__((ext_vector_type(4))) float f32x4;

__device__ __forceinline__ f32x4 mfma16(bf16x8 a, bf16x8 b, f32x4 c){
    return __builtin_amdgcn_mfma_f32_16x16x32_bf16(a, b, c, 0, 0, 0);
}

// ---------------------------------------------------------------------------
// Prep (fp32 inputs): h fp32 master + bf16 copy; bf16-transposed weights.
// ---------------------------------------------------------------------------
__global__ __launch_bounds__(256) void k_prep(
    const float* __restrict__ node, const float* __restrict__ Wmsg,
    const float* __restrict__ Wi,   const float* __restrict__ Wh,
    const float* __restrict__ Ar,
    float* __restrict__ h32, bf16* __restrict__ hb,
    bf16* __restrict__ WmT, bf16* __restrict__ WiT, bf16* __restrict__ WhT,
    bf16* __restrict__ ArT)
{
    int tid = blockIdx.x*256 + threadIdx.x;
    int stride = gridDim.x*256;
    for (int i = tid; i < Nn*Dd; i += stride){
        float v = node[i]; h32[i] = v; hb[i] = (bf16)v;
    }
    for (int i = tid; i < Ee*Dd*Dd; i += stride){
        int e = i >> 14; int r = i & 16383; int h = r >> 7; int d = r & 127;
        WmT[i] = (bf16)Wmsg[e*Dd*Dd + d*Dd + h];
    }
    for (int i = tid; i < 384*Dd; i += stride){
        int j = i >> 7; int d = i & 127;
        WiT[i] = (bf16)Wi[d*384 + j];
        WhT[i] = (bf16)Wh[d*384 + j];
    }
    for (int i = tid; i < Dd*Dd; i += stride){
        int h = i >> 7; int d = i & 127;
        ArT[i] = (bf16)Ar[d*Dd + h];
    }
}

// ---------------------------------------------------------------------------
// Edge fp32 -> bf16 once (~67MB read, one-time).
// ---------------------------------------------------------------------------
__global__ __launch_bounds__(256) void k_prep_edge(
    const float* __restrict__ edge, bf16* __restrict__ edge_bf)
{
    const size_t total = (size_t)Nn*Nn*Ee;
    size_t base = ((size_t)blockIdx.x*256 + threadIdx.x)*8;
    size_t stride = (size_t)gridDim.x*256*8;
    for (size_t i = base; i < total; i += stride){
        f32x4 v0 = *(const f32x4*)&edge[i];
        f32x4 v1 = *(const f32x4*)&edge[i+4];
        bf16x8 o;
        for (int j = 0; j < 4; j++){ o[j] = (bf16)v0[j]; o[j+4] = (bf16)v1[j]; }
        *(bf16x8*)&edge_bf[i] = o;
    }
}

// ---------------------------------------------------------------------------
// Per-edge transform, ALL 8 edge types per block:
//   Pt[h][s*8+e] = (hb @ W_e)[s][h]   -> 16B bf16x8 stores
// grid (32 s-tiles of 64, 8 h-tiles of 16), block 256
// ---------------------------------------------------------------------------
__global__ __launch_bounds__(256) void k_per_edge(
    const bf16* __restrict__ hb, const bf16* __restrict__ WmT,
    bf16* __restrict__ Pt)
{
    __shared__ bf16 Blds[Ee][16][Dd+8];
    const int s0 = blockIdx.x * 64;
    const int h0 = blockIdx.y * 16;
    const int tid = threadIdx.x;
    for (int i = 0; i < 8; i++){
        int idx = tid + i*256;
        int e = idx >> 8, row = (idx >> 4) & 15, c = idx & 15;
        *(bf16x8*)&Blds[e][row][c*8] =
            *(const bf16x8*)&WmT[e*Dd*Dd + (h0+row)*Dd + c*8];
    }
    __syncthreads();
    const int lane = tid & 63, wave = tid >> 6;
    const int quad = lane >> 4, l16 = lane & 15;
    const int srow = s0 + wave*16 + l16;
    f32x4 acc[Ee];
    for (int e = 0; e < Ee; e++) acc[e] = (f32x4){0.f,0.f,0.f,0.f};
    for (int kk = 0; kk < 4; kk++){
        int k0 = kk*32 + quad*8;
        bf16x8 a = *(const bf16x8*)&hb[srow*Dd + k0];
        for (int e = 0; e < Ee; e++){
            bf16x8 b = *(const bf16x8*)&Blds[e][l16][k0];
            acc[e] = mfma16(a, b, acc[e]);
        }
    }
    const int h = h0 + l16;
    for (int r = 0; r < 4; r++){
        int s = s0 + wave*16 + quad*4 + r;
        bf16x8 po;
        for (int e = 0; e < Ee; e++) po[e] = (bf16)acc[e][r];
        *(bf16x8*)&Pt[(size_t)h*KT + s*Ee] = po;
    }
}

// ---------------------------------------------------------------------------
// msgP[ks][t][h] = sum_{k in split} A[t][k]*Pt[h][k],  A[t][k]=edge[s][t][e]
// m97-style: BM=128, BN=128(all h), BK=64. 4 waves in 2x2, each 64x64 via
// 4x4 fragments -> 16 MFMA per 8 ds_read_b128. A and B both LDS-staged;
// A chunk = 8 s-slices, each 2KB contiguous in native edge layout.
// grid (16 t-tiles, KSPLIT), block 256.
// ---------------------------------------------------------------------------
__global__ __launch_bounds__(256) void k_msg_gemm(
    const bf16* __restrict__ edge_bf, const bf16* __restrict__ Pt,
    float* __restrict__ msgP)
{
    __shared__ __align__(16) bf16 Alds[8][1032];    // 8 s-slices x 128t*8e, +16B pad
    __shared__ __align__(16) bf16 Blds[128][72];    // 128 h x 64 k, +16B pad
    const int t0 = blockIdx.x * 128;
    const int kbase = blockIdx.y * (KT/KSPLIT);     // 1024 k = 128 s
    const int tid = threadIdx.x;
    const int lane = tid & 63, wave = tid >> 6;
    const int quad = lane >> 4, l16 = lane & 15;
    const int wm = wave & 1, wn = wave >> 1;

    f32x4 acc[4][4];
    for (int mt = 0; mt < 4; mt++)
        for (int nt = 0; nt < 4; nt++) acc[mt][nt] = (f32x4){0.f,0.f,0.f,0.f};

    for (int ch = 0; ch < 16; ch++){
        const int kc = kbase + ch*64;
        const int sb = kc >> 3;
        // stage A: 8 slices x 1024 elems (each slice contiguous 2KB in edge)
        for (int i = 0; i < 4; i++){
            int idx = tid + i*256;                  // 1024 chunks of 16B
            int sl = idx >> 7, off = idx & 127;
            *(bf16x8*)&Alds[sl][off*8] =
                *(const bf16x8*)&edge_bf[(size_t)(sb+sl)*(Nn*Ee) + (size_t)(t0+off)*Ee];
        }
        // stage B: 128 rows x 64 k
        for (int i = 0; i < 4; i++){
            int idx = tid + i*256;
            int row = idx >> 3, c = idx & 7;
            *(bf16x8*)&Blds[row][c*8] =
                *(const bf16x8*)&Pt[(size_t)row*KT + kc + c*8];
        }
        __syncthreads();
        for (int kk = 0; kk < 2; kk++){
            const int sl = kk*4 + quad;
            const int klb = kk*32 + quad*8;
            bf16x8 a[4], b[4];
            for (int mt = 0; mt < 4; mt++){
                int tp = wm*64 + mt*16 + l16;
                a[mt] = *(const bf16x8*)&Alds[sl][tp*8];
            }
            for (int nt = 0; nt < 4; nt++){
                int n = wn*64 + nt*16 + l16;
                b[nt] = *(const bf16x8*)&Blds[n][klb];
            }
            for (int mt = 0; mt < 4; mt++)
                for (int nt = 0; nt < 4; nt++)
                    acc[mt][nt] = mfma16(a[mt], b[nt], acc[mt][nt]);
        }
        __syncthreads();
    }
    float* dst = msgP + (size_t)blockIdx.y*Nn*Dd;
    for (int mt = 0; mt < 4; mt++){
        for (int nt = 0; nt < 4; nt++){
            int h = wn*64 + nt*16 + l16;
            for (int r = 0; r < 4; r++){
                int t = t0 + wm*64 + mt*16 + quad*4 + r;
                dst[(size_t)t*Dd + h] = acc[mt][nt][r];
            }
        }
    }
}

// ---------------------------------------------------------------------------
// GRU: messages = sum_ks msgP + b_msg (folded into A build);
// Gi = msg@Wi, Gh = h@Wh, gates, h update. fp32 master + bf16 copy.
// ---------------------------------------------------------------------------
__global__ __launch_bounds__(256) void k_gru(
    const float* __restrict__ msgP, const bf16* __restrict__ WiT,
    const bf16* __restrict__ WhT, const float* __restrict__ bmsg,
    const float* __restrict__ bgru,
    float* __restrict__ h32, bf16* __restrict__ hb)
{
    __shared__ __align__(16) bf16 stage[384][40];
    __shared__ float Gs[16][384];
    __shared__ float Ghn[16][128];

    const int t0 = blockIdx.x * 16;
    const int tid = threadIdx.x;
    const int lane = tid & 63, wave = tid >> 6;
    const int quad = lane >> 4, l16 = lane & 15;

    f32x4 accA[6], accB[6];
    for (int i = 0; i < 6; i++){ accA[i] = (f32x4){0.f,0.f,0.f,0.f}; accB[i] = (f32x4){0.f,0.f,0.f,0.f}; }

    for (int mat = 0; mat < 2; mat++){
        const bf16* WT = mat == 0 ? WiT : WhT;
        for (int kc = 0; kc < 4; kc++){
            for (int i = 0; i < 6; i++){
                int idx = tid + i*256; int row = idx >> 2, c = idx & 3;
                *(bf16x8*)&stage[row][c*8] = *(const bf16x8*)&WT[row*Dd + kc*32 + c*8];
            }
            __syncthreads();
            int k0 = kc*32 + quad*8;
            bf16x8 a;
            if (mat == 0){
                const float* mp = &msgP[(size_t)(t0 + l16)*Dd + k0];
                f32x4 s0 = *(const f32x4*)&bmsg[k0];
                f32x4 s1 = *(const f32x4*)&bmsg[k0+4];
                for (int p = 0; p < KSPLIT; p++){
                    s0 += *(const f32x4*)&mp[(size_t)p*Nn*Dd];
                    s1 += *(const f32x4*)&mp[(size_t)p*Nn*Dd + 4];
                }
                for (int j = 0; j < 4; j++){ a[j] = (bf16)s0[j]; a[j+4] = (bf16)s1[j]; }
            } else {
                a = *(const bf16x8*)&hb[(t0 + l16)*Dd + k0];
            }
            for (int tt = 0; tt < 6; tt++){
                int T = wave*6 + tt;
                bf16x8 b = *(const bf16x8*)&stage[T*16 + l16][quad*8];
                if (mat == 0 || T < 16) accA[tt] = mfma16(a, b, accA[tt]);
                else                    accB[tt] = mfma16(a, b, accB[tt]);
            }
            __syncthreads();
        }
    }
    for (int tt = 0; tt < 6; tt++){
        int T = wave*6 + tt;
        int j = T*16 + l16;
        for (int r = 0; r < 4; r++){
            int m = quad*4 + r;
            Gs[m][j] = accA[tt][r];
            if (T >= 16) Ghn[m][j - 256] = accB[tt][r];
        }
    }
    __syncthreads();
    for (int i = 0; i < 8; i++){
        int cell = tid + i*256;
        int m = cell >> 7, jd = cell & 127;
        int t = t0 + m;
        float xr = Gs[m][jd]       + bgru[jd];
        float xz = Gs[m][jd + 128] + bgru[jd + 128];
        float xn = Gs[m][jd + 256] + bgru[jd + 256];
        float r = 1.f / (1.f + expf(-xr));
        float z = 1.f / (1.f + expf(-xz));
        float n = tanhf(xn + r * Ghn[m][jd]);
        float ho = h32[t*Dd + jd];
        float hnew = (1.f - z) * n + z * ho;
        h32[t*Dd + jd] = hnew;
        hb [t*Dd + jd] = (bf16)hnew;
    }
}

// ---------------------------------------------------------------------------
// Readout 1: t1 = hb @ A_readout  (via ArT[h][d]), bf16 out (internal)
// ---------------------------------------------------------------------------
__global__ __launch_bounds__(256) void k_read1(
    const bf16* __restrict__ hb, const bf16* __restrict__ ArT, bf16* __restrict__ t1)
{
    __shared__ bf16 Blds[Dd][Dd+8];
    const int s0 = blockIdx.x * 64;
    const int tid = threadIdx.x;
    for (int i = 0; i < 8; i++){
        int idx = tid + i*256; int row = idx >> 4, c = idx & 15;
        *(bf16x8*)&Blds[row][c*8] = *(const bf16x8*)&ArT[row*Dd + c*8];
    }
    __syncthreads();
    const int lane = tid & 63, wave = tid >> 6;
    const int quad = lane >> 4, l16 = lane & 15;
    const int srow = s0 + wave*16 + l16;
    f32x4 acc[8];
    for (int nt = 0; nt < 8; nt++) acc[nt] = (f32x4){0.f,0.f,0.f,0.f};
    for (int kk = 0; kk < 4; kk++){
        int k0 = kk*32 + quad*8;
        bf16x8 a = *(const bf16x8*)&hb[srow*Dd + k0];
        for (int nt = 0; nt < 8; nt++){
            bf16x8 b = *(const bf16x8*)&Blds[nt*16 + l16][k0];
            acc[nt] = mfma16(a, b, acc[nt]);
        }
    }
    for (int nt = 0; nt < 8; nt++){
        int h = nt*16 + l16;
        for (int r = 0; r < 4; r++){
            int s = s0 + wave*16 + quad*4 + r;
            t1[s*Dd + h] = (bf16)acc[nt][r];
        }
    }
}

// ---------------------------------------------------------------------------
// Readout 2: logits[i][j] = sum_d t1[i][d]*hb[j][d], fp32 out
// ---------------------------------------------------------------------------
__global__ __launch_bounds__(256) void k_read2(
    const bf16* __restrict__ t1, const bf16* __restrict__ hb, float* __restrict__ out)
{
    const int i0 = blockIdx.x * 64, j0 = blockIdx.y * 128;
    const int tid = threadIdx.x;
    const int lane = tid & 63, wave = tid >> 6;
    const int quad = lane >> 4, l16 = lane & 15;
    const int irow = i0 + wave*16 + l16;
    f32x4 acc[8];
    for (int nt = 0; nt < 8; nt++) acc[nt] = (f32x4){0.f,0.f,0.f,0.f};
    for (int kk = 0; kk < 4; kk++){
        int k0 = kk*32 + quad*8;
        bf16x8 a = *(const bf16x8*)&t1[irow*Dd + k0];
        for (int nt = 0; nt < 8; nt++){
            int j = j0 + nt*16 + l16;
            bf16x8 b = *(const bf16x8*)&hb[j*Dd + k0];
            acc[nt] = mfma16(a, b, acc[nt]);
        }
    }
    for (int nt = 0; nt < 8; nt++){
        int j = j0 + nt*16 + l16;
        for (int r = 0; r < 4; r++){
            int irw = i0 + wave*16 + quad*4 + r;
            out[(size_t)irw*Nn + j] = acc[nt][r];
        }
    }
}

// ---------------------------------------------------------------------------
extern "C" void kernel_launch(void* const* d_in, const int* in_sizes, int n_in,
                              void* d_out, int out_size, void* d_ws, size_t ws_size,
                              hipStream_t stream)
{
    const float* node = (const float*)d_in[0];
    const float* edge = (const float*)d_in[1];
    const float* Wmsg = (const float*)d_in[2];
    const float* bmsg = (const float*)d_in[3];
    const float* Wi   = (const float*)d_in[4];
    const float* Wh   = (const float*)d_in[5];
    const float* bgru = (const float*)d_in[6];
    const float* Ar   = (const float*)d_in[7];
    float* out = (float*)d_out;

    char* ws = (char*)d_ws;
    bf16*  edge_bf = (bf16*)ws;          ws += (size_t)Nn*Nn*Ee*2;      // 64 MiB
    float* msgP = (float*)ws;            ws += (size_t)KSPLIT*Nn*Dd*4;  // 16 MiB
    bf16*  Pt  = (bf16*)ws;              ws += (size_t)Dd*KT*2;         //  4 MiB
    float* h32 = (float*)ws;             ws += (size_t)Nn*Dd*4;
    bf16*  hb  = (bf16*)ws;              ws += (size_t)Nn*Dd*2;
    bf16*  WmT = (bf16*)ws;              ws += (size_t)Ee*Dd*Dd*2;
    bf16*  WiT = (bf16*)ws;              ws += (size_t)384*Dd*2;
    bf16*  WhT = (bf16*)ws;              ws += (size_t)384*Dd*2;
    bf16*  ArT = (bf16*)ws;              ws += (size_t)Dd*Dd*2;
    bf16*  t1  = (bf16*)ws;              ws += (size_t)Nn*Dd*2;

    k_prep<<<dim3(256), 256, 0, stream>>>(node, Wmsg, Wi, Wh, Ar,
                                          h32, hb, WmT, WiT, WhT, ArT);
    k_prep_edge<<<dim3(4096), 256, 0, stream>>>(edge, edge_bf);
    for (int it = 0; it < NIT; it++){
        k_per_edge<<<dim3(32, 8),      256, 0, stream>>>(hb, WmT, Pt);
        k_msg_gemm<<<dim3(16, KSPLIT), 256, 0, stream>>>(edge_bf, Pt, msgP);
        k_gru     <<<dim3(128),        256, 0, stream>>>(msgP, WiT, WhT, bmsg, bgru, h32, hb);
    }
    k_read1<<<dim3(32),     256, 0, stream>>>(hb, ArT, t1);
    k_read2<<<dim3(32, 16), 256, 0, stream>>>(t1, hb, out);
}